// Round 1
// baseline (3582.993 us; speedup 1.0000x reference)
//
#include <hip/hip_runtime.h>
#include <stdint.h>
#include <math.h>

// Replicate jax.random threefry2x32 exactly.
// PARTITIONABLE=1 -> jax_threefry_partitionable=True semantics (JAX >= 0.4.36 default):
//   split: key_i = threefry(key, (0, i)) (both words)
//   random_bits(32): bits[m] = x0 ^ x1 of threefry(key, (0, m))
// PARTITIONABLE=0 -> original scheme (iota halves pairing).
#define PARTITIONABLE 1

namespace {

constexpr int kB = 4096;
constexpr int kN = 256;
constexpr int kSweeps = 200;
constexpr int kSamp = 8;                 // samples per block
constexpr int kBlocks = kB / kSamp;      // 512

struct K2 { uint32_t a, b; };

__host__ __device__ constexpr uint32_t crotl(uint32_t x, int d) {
  return (x << d) | (x >> (32 - d));
}

// Threefry-2x32, 20 rounds, exactly as jax/_src/prng.py
__host__ __device__ constexpr K2 ctf(uint32_t k0, uint32_t k1, uint32_t c0, uint32_t c1) {
  uint32_t ks0 = k0, ks1 = k1, ks2 = k0 ^ k1 ^ 0x1BD11BDAu;
  uint32_t x0 = c0 + ks0, x1 = c1 + ks1;
  const int r0[4] = {13, 15, 26, 6};
  const int r1[4] = {17, 29, 16, 24};
  for (int i = 0; i < 4; ++i) { x0 += x1; x1 = crotl(x1, r0[i]); x1 ^= x0; }
  x0 += ks1; x1 += ks2 + 1u;
  for (int i = 0; i < 4; ++i) { x0 += x1; x1 = crotl(x1, r1[i]); x1 ^= x0; }
  x0 += ks2; x1 += ks0 + 2u;
  for (int i = 0; i < 4; ++i) { x0 += x1; x1 = crotl(x1, r0[i]); x1 ^= x0; }
  x0 += ks0; x1 += ks1 + 3u;
  for (int i = 0; i < 4; ++i) { x0 += x1; x1 = crotl(x1, r1[i]); x1 ^= x0; }
  x0 += ks1; x1 += ks2 + 4u;
  for (int i = 0; i < 4; ++i) { x0 += x1; x1 = crotl(x1, r0[i]); x1 ^= x0; }
  x0 += ks2; x1 += ks0 + 5u;
  return K2{x0, x1};
}

struct KeyTable {
  uint32_t s0k[2];               // key for initial spins (k0)
  uint32_t sk[kSweeps][4];       // per sweep: k1a,k1b (accept), k2a,k2b (mask)
};

constexpr KeyTable make_keys() {
  KeyTable t{};
  K2 root{0u, 42u};              // jax.random.key(42) -> (hi=0, lo=42)
#if PARTITIONABLE
  K2 k0 = ctf(root.a, root.b, 0u, 0u);
  K2 kl = ctf(root.a, root.b, 0u, 1u);
#else
  // original split(root,2): counts 0..3, pairs (0,2),(1,3); reshape(2,2)
  K2 p0 = ctf(root.a, root.b, 0u, 2u);
  K2 p1 = ctf(root.a, root.b, 1u, 3u);
  K2 k0{p0.a, p1.a};
  K2 kl{p0.b, p1.b};
#endif
  t.s0k[0] = k0.a; t.s0k[1] = k0.b;
  K2 k = kl;
  for (int s = 0; s < kSweeps; ++s) {
#if PARTITIONABLE
    K2 kn = ctf(k.a, k.b, 0u, 0u);
    K2 k1 = ctf(k.a, k.b, 0u, 1u);
    K2 k2 = ctf(k.a, k.b, 0u, 2u);
#else
    // original split(k,3): counts 0..5, pairs (0,3),(1,4),(2,5); reshape(3,2)
    K2 q0 = ctf(k.a, k.b, 0u, 3u);
    K2 q1 = ctf(k.a, k.b, 1u, 4u);
    K2 q2 = ctf(k.a, k.b, 2u, 5u);
    K2 kn{q0.a, q1.a};
    K2 k1{q2.a, q0.b};
    K2 k2{q1.b, q2.b};
#endif
    t.sk[s][0] = k1.a; t.sk[s][1] = k1.b;
    t.sk[s][2] = k2.a; t.sk[s][3] = k2.b;
    k = kn;
  }
  return t;
}

__constant__ KeyTable g_keys = make_keys();

__device__ __forceinline__ uint32_t rng_bits32(uint32_t ka, uint32_t kb, uint32_t m) {
#if PARTITIONABLE
  K2 r = ctf(ka, kb, 0u, m);
  return r.a ^ r.b;
#else
  constexpr uint32_t H = (uint32_t)(kB * kN / 2);
  uint32_t p = (m < H) ? m : (m - H);
  K2 r = ctf(ka, kb, p, p + H);
  return (m < H) ? r.a : r.b;
#endif
}

__device__ __forceinline__ float bits_to_uniform(uint32_t bits) {
  // jax: bitcast(bits >> 9 | 0x3f800000) - 1.0
  return __uint_as_float((bits >> 9) | 0x3f800000u) - 1.0f;
}

__global__ void prep_kernel(const float* __restrict__ gamma,
                            float* __restrict__ jsym,
                            float* __restrict__ betas) {
  int e = blockIdx.x * blockDim.x + threadIdx.x;   // 0..65535
  int i = e / kN, j = e % kN;
  float v = 0.0f;
  if (i < j) v = gamma[i * kN + j];
  else if (i > j) v = gamma[j * kN + i];
  jsym[e] = v;
  if (e < kSweeps) {
    double l0 = log(0.1), l1 = log(5.0);
    betas[e] = (float)exp(l0 + (l1 - l0) * (double)e / (double)(kSweeps - 1));
  }
}

__global__ __launch_bounds__(256) void anneal_kernel(
    const float* __restrict__ thetas, const float* __restrict__ jsym,
    const float* __restrict__ betas, float* __restrict__ out) {
  __shared__ __align__(16) float sh_s[kSamp][kN];   // spins as +-1.0f
  __shared__ float sh_red[kSamp][4];

  const int i = threadIdx.x;           // spin index
  const int b0 = blockIdx.x * kSamp;   // first sample of this block

  float th[kSamp], sreg[kSamp];
#pragma unroll
  for (int g = 0; g < kSamp; ++g) th[g] = thetas[(b0 + g) * kN + i];

  // s0 = where(bernoulli(k0, 0.5), 1, -1) ; bernoulli = uniform < 0.5
#pragma unroll
  for (int g = 0; g < kSamp; ++g) {
    uint32_t m = (uint32_t)((b0 + g) * kN + i);
    float u = bits_to_uniform(rng_bits32(g_keys.s0k[0], g_keys.s0k[1], m));
    float sv = (u < 0.5f) ? 1.0f : -1.0f;
    sreg[g] = sv;
    sh_s[g][i] = sv;
  }
  __syncthreads();

  // row i of Jsym; by symmetry local_i = sum_j Jsym[i][j] * s[j]
  const float4* __restrict__ jrow = (const float4*)(jsym + i * kN);

  for (int t = 0; t < kSweeps; ++t) {
    const float beta = betas[t];

    float acc[kSamp];
#pragma unroll
    for (int g = 0; g < kSamp; ++g) acc[g] = 0.0f;

    for (int jj = 0; jj < kN / 4; ++jj) {
      float4 jv = jrow[jj];
#pragma unroll
      for (int g = 0; g < kSamp; ++g) {
        float4 sv = *(const float4*)&sh_s[g][jj * 4];
        acc[g] = fmaf(jv.x, sv.x, acc[g]);
        acc[g] = fmaf(jv.y, sv.y, acc[g]);
        acc[g] = fmaf(jv.z, sv.z, acc[g]);
        acc[g] = fmaf(jv.w, sv.w, acc[g]);
      }
    }
    __syncthreads();   // everyone done reading sh_s

    const uint32_t k1a = g_keys.sk[t][0], k1b = g_keys.sk[t][1];
    const uint32_t k2a = g_keys.sk[t][2], k2b = g_keys.sk[t][3];
#pragma unroll
    for (int g = 0; g < kSamp; ++g) {
      float s = sreg[g];
      float local = th[g] + acc[g];
      float dE = -2.0f * s * local;          // exact: (-2*s) is a power of two
      float p = expf(-beta * dE);
      uint32_t m = (uint32_t)((b0 + g) * kN + i);
      float u1 = bits_to_uniform(rng_bits32(k1a, k1b, m));
      float u2 = bits_to_uniform(rng_bits32(k2a, k2b, m));
      if ((u1 < p) && (u2 < 0.5f)) {         // accept & mask
        s = -s;
        sreg[g] = s;
        sh_s[g][i] = s;
      }
    }
    __syncthreads();   // writes visible before next sweep reads
  }

  // E_b = sum_i s_i*theta_i + 0.5 * sum_i s_i * (Jsym s)_i
  float acc[kSamp];
#pragma unroll
  for (int g = 0; g < kSamp; ++g) acc[g] = 0.0f;
  for (int jj = 0; jj < kN / 4; ++jj) {
    float4 jv = jrow[jj];
#pragma unroll
    for (int g = 0; g < kSamp; ++g) {
      float4 sv = *(const float4*)&sh_s[g][jj * 4];
      acc[g] = fmaf(jv.x, sv.x, acc[g]);
      acc[g] = fmaf(jv.y, sv.y, acc[g]);
      acc[g] = fmaf(jv.z, sv.z, acc[g]);
      acc[g] = fmaf(jv.w, sv.w, acc[g]);
    }
  }

  const int lane = threadIdx.x & 63;
  const int wid = threadIdx.x >> 6;
#pragma unroll
  for (int g = 0; g < kSamp; ++g) {
    float v = sreg[g] * th[g] + 0.5f * (sreg[g] * acc[g]);
#pragma unroll
    for (int off = 32; off > 0; off >>= 1) v += __shfl_down(v, off);
    if (lane == 0) sh_red[g][wid] = v;
  }
  __syncthreads();
  if (threadIdx.x < kSamp) {
    int g = threadIdx.x;
    out[b0 + g] = sh_red[g][0] + sh_red[g][1] + sh_red[g][2] + sh_red[g][3];
  }
}

}  // namespace

extern "C" void kernel_launch(void* const* d_in, const int* in_sizes, int n_in,
                              void* d_out, int out_size, void* d_ws, size_t ws_size,
                              hipStream_t stream) {
  const float* thetas = (const float*)d_in[0];   // [4096, 256]
  const float* gamma  = (const float*)d_in[1];   // [256, 256]
  float* jsym  = (float*)d_ws;                              // 256 KiB
  float* betas = (float*)((char*)d_ws + kN * kN * sizeof(float));

  hipLaunchKernelGGL(prep_kernel, dim3(kN), dim3(kN), 0, stream, gamma, jsym, betas);
  hipLaunchKernelGGL(anneal_kernel, dim3(kBlocks), dim3(256), 0, stream,
                     thetas, jsym, betas, (float*)d_out);
}